// Round 5
// baseline (266.486 us; speedup 1.0000x reference)
//
#include <hip/hip_runtime.h>
#include <hip/hip_cooperative_groups.h>
namespace cg = cooperative_groups;

#define BB 4
#define TT 1024
#define DD 128
#define LL 16
#define CC 64   // TT/LL
#define EPSV 1e-6f

// workspace offsets (floats)
#define OFF_QC   0
#define OFF_KH   (OFF_QC + BB*TT*DD)
#define OFF_V    (OFF_KH + BB*TT*DD)
#define OFF_CL   (OFF_V  + BB*TT*DD)
#define OFF_KS   (OFF_CL + BB*CC*DD)
#define OFF_Z0   (OFF_KS + BB*CC*DD)
#define OFF_U    (OFF_Z0 + BB*CC*DD)
#define OFF_S0   (OFF_U  + BB*CC*DD*DD)
#define OFF_G    (OFF_S0 + BB*CC*DD*DD)

struct P1 { float xs[32][DD]; float wsh[64][132]; };                       // 50.0 KB
struct P2 { float qs[LL][DD]; float ksm[LL][DD]; float vs[LL][DD];
            float gs[LL][DD]; float kbs[LL][DD]; };                       // 40 KB
struct P3 { float cls[2][CC]; float kss[2][CC]; };                        // 1 KB
struct P4 { float qcs[LL][DD+4]; float khs[LL][DD+4]; float vsm[LL][DD+4];
            float Ss[LL][LL]; float denS[LL]; float z0s[DD];
            float s0s[2][32][DD]; };                                      // 58.3 KB
union SMem { P1 p1; P2 p2; P3 p3; P4 p4; };

// ---------------------------------------------------------------------------
// One cooperative dispatch, 256 blocks x 256 threads (1 block/CU), 4 phases
// separated by grid.sync(). Phase bodies identical math to the R4 4-kernel
// pipeline; only the job->block mapping changed.
// ---------------------------------------------------------------------------
__global__ __launch_bounds__(256, 1) void k_fused(
    const float* __restrict__ x,
    const float* __restrict__ Wq, const float* __restrict__ bq,
    const float* __restrict__ Wk, const float* __restrict__ bk,
    const float* __restrict__ Wv, const float* __restrict__ bv,
    const float* __restrict__ Wa, const float* __restrict__ ba,
    float* __restrict__ ws, float* __restrict__ y)
{
    __shared__ SMem sm;
    cg::grid_group grid = cg::this_grid();
    const int tid = threadIdx.x;
    const int blk = blockIdx.x;

    // ================= phase 1: fused 4-projection GEMM =================
    // job = (rt, m, jh); this block keeps (m,jh) fixed -> stage W half once,
    // then 4 row-tiles rt = (blk>>3) + 32*r.
    {
        const int mt = blk & 7;
        const int m  = mt >> 1;            // 0:q 1:k 2:v 3:a
        const int jh = mt & 1;             // column half
        const float* W    = (m==0)?Wq : (m==1)?Wk : (m==2)?Wv : Wa;
        const float* bias = (m==0)?bq : (m==1)?bk : (m==2)?bv : ba;

        const float4* wg = (const float4*)(W + (size_t)jh*64*DD);
        #pragma unroll
        for (int r=0;r<8;r++){
            int f = tid + r*256;
            *(float4*)&sm.p1.wsh[f>>5][(f&31)*4] = wg[f];
        }

        const int ci = tid & 15;
        const int ri = tid >> 4;
        float bias0[4];
        #pragma unroll
        for (int cc=0;cc<4;cc++) bias0[cc] = bias[jh*64 + ci + 16*cc];
        float* dst = ws + ((m==0)?OFF_QC : (m==1)?OFF_KH : (m==2)?OFF_V : OFF_G);

        for (int r4=0; r4<4; r4++){
            const int rt = (blk >> 3) + 32*r4;
            __syncthreads();               // xs free (prev iter readers done)
            const float4* xg = (const float4*)(x + (size_t)rt*32*DD);
            #pragma unroll
            for (int r=0;r<4;r++){
                int f = tid + r*256;
                *(float4*)&sm.p1.xs[f>>5][(f&31)*4] = xg[f];
            }
            __syncthreads();

            float acc[2][4];
            #pragma unroll
            for (int cc=0;cc<4;cc++){ acc[0][cc]=bias0[cc]; acc[1][cc]=bias0[cc]; }

            #pragma unroll 2
            for (int k4=0; k4<32; k4++){
                float4 xa = *(const float4*)&sm.p1.xs[ri   ][k4*4];
                float4 xb = *(const float4*)&sm.p1.xs[ri+16][k4*4];
                #pragma unroll
                for (int cc=0;cc<4;cc++){
                    float4 w = *(const float4*)&sm.p1.wsh[ci+16*cc][k4*4];
                    acc[0][cc] = fmaf(xa.x,w.x, fmaf(xa.y,w.y, fmaf(xa.z,w.z, fmaf(xa.w,w.w, acc[0][cc]))));
                    acc[1][cc] = fmaf(xb.x,w.x, fmaf(xb.y,w.y, fmaf(xb.z,w.z, fmaf(xb.w,w.w, acc[1][cc]))));
                }
            }

            #pragma unroll
            for (int rr=0;rr<2;rr++){
                int row = rt*32 + ri + 16*rr;
                #pragma unroll
                for (int cc=0;cc<4;cc++){
                    float v = acc[rr][cc];
                    if (m==0 || m==1) v = fmaxf(v, 0.f);
                    else if (m==3)    v = 1.f/(1.f+__expf(-v));
                    dst[(size_t)row*DD + jh*64 + ci + 16*cc] = v;
                }
            }
        }
    }
    grid.sync();

    // ================= phase 2: per-chunk postprocess (bc = blk) ========
    {
        const int bc = blk;
        const int b  = bc / CC;
        const int t0 = (bc % CC) * LL;
        const size_t tile = (size_t)(b*TT + t0)*DD;

        {
            const float4* qg = (const float4*)(ws + OFF_QC + tile);
            const float4* kg = (const float4*)(ws + OFF_KH + tile);
            const float4* vg = (const float4*)(ws + OFF_V  + tile);
            const float4* gg = (const float4*)(ws + OFF_G  + tile);
            #pragma unroll
            for (int r=0;r<2;r++){
                int f = tid + r*256;
                int t = f >> 5, c4 = (f & 31)*4;
                *(float4*)&sm.p2.qs [t][c4] = qg[f];
                *(float4*)&sm.p2.ksm[t][c4] = kg[f];
                *(float4*)&sm.p2.vs [t][c4] = vg[f];
                *(float4*)&sm.p2.gs [t][c4] = gg[f];
            }
        }
        __syncthreads();

        if (tid < DD){
            float c = 1.f;
            #pragma unroll
            for (int t=0;t<LL;t++){ c *= sm.p2.gs[t][tid]; sm.p2.gs[t][tid] = c; }
            ws[OFF_CL + (size_t)bc*DD + tid] = c;
        }
        __syncthreads();

        if (tid < DD){                     // waves 0-1: kh, kb, Ksum
            const int j = tid;
            const float cl = sm.p2.gs[LL-1][j];
            float ksum = 0.f;
            float* khg = ws + OFF_KH + tile;
            #pragma unroll
            for (int t=0;t<LL;t++){
                float kh = sm.p2.ksm[t][j] / sm.p2.gs[t][j];
                khg[t*DD + j] = kh;
                float kb = kh * cl;
                sm.p2.kbs[t][j] = kb;
                ksum += kb;
            }
            ws[OFF_KS + (size_t)bc*DD + j] = ksum;
        } else {                           // waves 2-3: qc
            const int j = tid - DD;
            float* qcg = ws + OFF_QC + tile;
            #pragma unroll
            for (int t=0;t<LL;t++)
                qcg[t*DD + j] = sm.p2.qs[t][j] * sm.p2.gs[t][j];
        }
        __syncthreads();

        // U[i][j] = sum_u kb[u][i]*v[u][j]
        const int j  = tid & 127;
        const int ih = tid >> 7;
        float vr[LL];
        #pragma unroll
        for (int u=0;u<LL;u++) vr[u]=sm.p2.vs[u][j];
        float* Ug = ws + OFF_U + (size_t)bc*DD*DD;
        #pragma unroll 2
        for (int i4=0;i4<16;i4++){
            int i = ih*64 + i4*4;
            float a0=0.f,a1=0.f,a2=0.f,a3=0.f;
            #pragma unroll
            for (int u=0;u<LL;u++){
                float4 kb4 = *(const float4*)(&sm.p2.kbs[u][i]);
                float vu = vr[u];
                a0 = fmaf(kb4.x,vu,a0); a1 = fmaf(kb4.y,vu,a1);
                a2 = fmaf(kb4.z,vu,a2); a3 = fmaf(kb4.w,vu,a3);
            }
            Ug[(size_t)(i+0)*DD + j]=a0; Ug[(size_t)(i+1)*DD + j]=a1;
            Ug[(size_t)(i+2)*DD + j]=a2; Ug[(size_t)(i+3)*DD + j]=a3;
        }
    }
    grid.sync();

    // ================= phase 3: chunk scan (2 jobs/block) ===============
    {
        const int h   = tid >> 7;          // which job half
        const int jl  = tid & 127;
        const int job = blk*2 + h;         // (b,i), 512 jobs
        const int b   = job >> 7;
        const int i   = job & 127;

        if (jl < CC) sm.p3.cls[h][jl]      = ws[OFF_CL + (size_t)(b*CC + jl)*DD + i];
        else         sm.p3.kss[h][jl - CC] = ws[OFF_KS + (size_t)(b*CC + jl - CC)*DD + i];
        __syncthreads();

        const float* U  = ws + OFF_U;
        float*       s0 = ws + OFF_S0;
        float*       z0 = ws + OFF_Z0;
        const size_t base = (size_t)b*CC*DD*DD + (size_t)i*DD + jl;

        float up[8];
        #pragma unroll
        for (int p=0;p<8;p++) up[p] = U[base + (size_t)p*DD*DD];

        float s = 0.f, z = 0.f;
        #pragma unroll
        for (int ch=0; ch<CC; ch++){
            s0[base + (size_t)ch*DD*DD] = s;
            if (jl==0) z0[(size_t)(b*CC+ch)*DD + i] = z;
            float u  = up[ch & 7];
            if (ch + 8 < CC) up[ch & 7] = U[base + (size_t)(ch+8)*DD*DD];
            float cl = sm.p3.cls[h][ch];
            s = fmaf(cl, s, u);
            z = fmaf(cl, z, sm.p3.kss[h][ch]);
        }
    }
    grid.sync();

    // ================= phase 4: output (bc = blk) =======================
    {
        const int bc = blk;
        const int b  = bc / CC;
        const int ch = bc % CC;
        const int t0 = ch * LL;
        const float* s0g = ws + OFF_S0 + (size_t)bc*DD*DD;

        float4 pre[4];
        {
            const float4* qcg = (const float4*)(ws + OFF_QC + (size_t)(b*TT+t0)*DD);
            const float4* khg = (const float4*)(ws + OFF_KH + (size_t)(b*TT+t0)*DD);
            const float4* vg  = (const float4*)(ws + OFF_V  + (size_t)(b*TT+t0)*DD);
            #pragma unroll
            for (int rep=0; rep<2; rep++){
                int f = tid + rep*256;
                int t = f >> 5, k4 = f & 31;
                *(float4*)&sm.p4.qcs[t][k4*4] = qcg[f];
                *(float4*)&sm.p4.khs[t][k4*4] = khg[f];
                *(float4*)&sm.p4.vsm[t][k4*4] = vg [f];
            }
            if (tid < DD) sm.p4.z0s[tid] = ws[OFF_Z0 + (size_t)bc*DD + tid];
            const float4* sg = (const float4*)s0g;
            #pragma unroll
            for (int r=0;r<4;r++) pre[r] = sg[tid + r*256];   // slice 0
        }
        __syncthreads();

        {
            int t = tid >> 4, u = tid & 15;
            float s = 0.f;
            #pragma unroll 8
            for (int k4=0; k4<32; k4++){
                float4 q4 = *(const float4*)&sm.p4.qcs[t][k4*4];
                float4 h4 = *(const float4*)&sm.p4.khs[u][k4*4];
                s = fmaf(q4.x,h4.x, fmaf(q4.y,h4.y, fmaf(q4.z,h4.z, fmaf(q4.w,h4.w, s))));
            }
            sm.p4.Ss[t][u] = (u <= t) ? s : 0.f;
        }
        __syncthreads();

        if (tid < LL){
            int t = tid;
            float d = EPSV;
            for (int u=0; u<=t; u++) d += sm.p4.Ss[t][u];
            #pragma unroll 8
            for (int kk=0; kk<DD; kk++) d += sm.p4.qcs[t][kk]*sm.p4.z0s[kk];
            sm.p4.denS[t] = d;
        }

        const int t  = tid >> 4;
        const int jg = tid & 15;
        const int j0 = jg * 8;
        float y8[8];
        #pragma unroll
        for (int jj=0;jj<8;jj++) y8[jj]=0.f;

        __syncthreads();
        #pragma unroll
        for (int u=0; u<LL; u++){
            float sv = sm.p4.Ss[t][u];
            float4 v4a = *(const float4*)&sm.p4.vsm[u][j0];
            float4 v4b = *(const float4*)&sm.p4.vsm[u][j0+4];
            y8[0]=fmaf(sv,v4a.x,y8[0]); y8[1]=fmaf(sv,v4a.y,y8[1]);
            y8[2]=fmaf(sv,v4a.z,y8[2]); y8[3]=fmaf(sv,v4a.w,y8[3]);
            y8[4]=fmaf(sv,v4b.x,y8[4]); y8[5]=fmaf(sv,v4b.y,y8[5]);
            y8[6]=fmaf(sv,v4b.z,y8[6]); y8[7]=fmaf(sv,v4b.w,y8[7]);
        }

        #pragma unroll
        for (int sl=0; sl<4; sl++){
            __syncthreads();
            {
                float* dstb = &sm.p4.s0s[sl&1][0][0];
                #pragma unroll
                for (int r=0;r<4;r++) *(float4*)(dstb + (tid + r*256)*4) = pre[r];
            }
            if (sl < 3){
                const float4* sg = (const float4*)(s0g + (size_t)(sl+1)*32*DD);
                #pragma unroll
                for (int r=0;r<4;r++) pre[r] = sg[tid + r*256];
            }
            __syncthreads();
            #pragma unroll 8
            for (int ii=0; ii<32; ii++){
                float qv = sm.p4.qcs[t][sl*32+ii];
                float4 s4a = *(const float4*)&sm.p4.s0s[sl&1][ii][j0];
                float4 s4b = *(const float4*)&sm.p4.s0s[sl&1][ii][j0+4];
                y8[0]=fmaf(qv,s4a.x,y8[0]); y8[1]=fmaf(qv,s4a.y,y8[1]);
                y8[2]=fmaf(qv,s4a.z,y8[2]); y8[3]=fmaf(qv,s4a.w,y8[3]);
                y8[4]=fmaf(qv,s4b.x,y8[4]); y8[5]=fmaf(qv,s4b.y,y8[5]);
                y8[6]=fmaf(qv,s4b.z,y8[6]); y8[7]=fmaf(qv,s4b.w,y8[7]);
            }
        }

        const float rd = 1.f/sm.p4.denS[t];
        float* yg = y + (size_t)(b*TT + t0 + t)*DD + j0;
        float4 o0 = make_float4(y8[0]*rd, y8[1]*rd, y8[2]*rd, y8[3]*rd);
        float4 o1 = make_float4(y8[4]*rd, y8[5]*rd, y8[6]*rd, y8[7]*rd);
        *(float4*)(yg)     = o0;
        *(float4*)(yg + 4) = o1;
    }
}

extern "C" void kernel_launch(void* const* d_in, const int* in_sizes, int n_in,
                              void* d_out, int out_size, void* d_ws, size_t ws_size,
                              hipStream_t stream)
{
    const float* x  = (const float*)d_in[0];
    const float* Wq = (const float*)d_in[1]; const float* bq = (const float*)d_in[2];
    const float* Wk = (const float*)d_in[3]; const float* bk = (const float*)d_in[4];
    const float* Wv = (const float*)d_in[5]; const float* bv = (const float*)d_in[6];
    const float* Wa = (const float*)d_in[7]; const float* ba = (const float*)d_in[8];
    float* ws = (float*)d_ws;
    float* yo = (float*)d_out;

    void* args[] = { (void*)&x,
                     (void*)&Wq, (void*)&bq, (void*)&Wk, (void*)&bk,
                     (void*)&Wv, (void*)&bv, (void*)&Wa, (void*)&ba,
                     (void*)&ws, (void*)&yo };
    hipLaunchCooperativeKernel((const void*)k_fused, dim3(256), dim3(256),
                               args, 0, stream);
}

// Round 6
// 117.050 us; speedup vs baseline: 2.2767x; 2.2767x over previous
//
#include <hip/hip_runtime.h>

#define BB 4
#define TT 1024
#define DD 128
#define LL 16
#define CC 64   // TT/LL
#define EPSV 1e-6f

// workspace offsets (floats)
#define OFF_QC   0
#define OFF_KH   (OFF_QC + BB*TT*DD)
#define OFF_V    (OFF_KH + BB*TT*DD)
#define OFF_CL   (OFF_V  + BB*TT*DD)
#define OFF_KS   (OFF_CL + BB*CC*DD)
#define OFF_Z0   (OFF_KS + BB*CC*DD)
#define OFF_U    (OFF_Z0 + BB*CC*DD)
#define OFF_S0   (OFF_U  + BB*CC*DD*DD)
#define OFF_G    (OFF_S0 + BB*CC*DD*DD)

// ---------------------------------------------------------------------------
// Kernel 1 (R4-identical, proven): fused 4-projection GEMM.
// 1024 blocks (128 row-tiles x 8 mat-halves), 50KB LDS -> 3 blocks/CU.
// ---------------------------------------------------------------------------
__global__ __launch_bounds__(256) void k_gemm(
    const float* __restrict__ x,
    const float* __restrict__ Wq, const float* __restrict__ bq,
    const float* __restrict__ Wk, const float* __restrict__ bk,
    const float* __restrict__ Wv, const float* __restrict__ bv,
    const float* __restrict__ Wa, const float* __restrict__ ba,
    float* __restrict__ ws)
{
    __shared__ float xs [32][DD];
    __shared__ float wsh[64][132];

    const int tid = threadIdx.x;
    const int bx  = blockIdx.x;
    const int rt  = bx >> 3;
    const int mt  = bx & 7;
    const int m   = mt >> 1;
    const int jh  = mt & 1;

    const float* W    = (m==0)?Wq : (m==1)?Wk : (m==2)?Wv : Wa;
    const float* bias = (m==0)?bq : (m==1)?bk : (m==2)?bv : ba;

    {
        const float4* xg = (const float4*)(x + (size_t)rt*32*DD);
        #pragma unroll
        for (int r=0;r<4;r++){
            int f = tid + r*256;
            *(float4*)&xs[f>>5][(f&31)*4] = xg[f];
        }
        const float4* wg = (const float4*)(W + (size_t)jh*64*DD);
        #pragma unroll
        for (int r=0;r<8;r++){
            int f = tid + r*256;
            *(float4*)&wsh[f>>5][(f&31)*4] = wg[f];
        }
    }
    __syncthreads();

    const int ci = tid & 15;
    const int ri = tid >> 4;

    float acc[2][4];
    #pragma unroll
    for (int cc=0;cc<4;cc++){
        float bv_ = bias[jh*64 + ci + 16*cc];
        acc[0][cc]=bv_; acc[1][cc]=bv_;
    }

    #pragma unroll 2
    for (int k4=0; k4<32; k4++){
        float4 xa = *(const float4*)&xs[ri   ][k4*4];
        float4 xb = *(const float4*)&xs[ri+16][k4*4];
        #pragma unroll
        for (int cc=0;cc<4;cc++){
            float4 w = *(const float4*)&wsh[ci+16*cc][k4*4];
            acc[0][cc] = fmaf(xa.x,w.x, fmaf(xa.y,w.y, fmaf(xa.z,w.z, fmaf(xa.w,w.w, acc[0][cc]))));
            acc[1][cc] = fmaf(xb.x,w.x, fmaf(xb.y,w.y, fmaf(xb.z,w.z, fmaf(xb.w,w.w, acc[1][cc]))));
        }
    }

    float* dst = ws + ((m==0)?OFF_QC : (m==1)?OFF_KH : (m==2)?OFF_V : OFF_G);
    #pragma unroll
    for (int rr=0;rr<2;rr++){
        int row = rt*32 + ri + 16*rr;
        #pragma unroll
        for (int cc=0;cc<4;cc++){
            float v = acc[rr][cc];
            if (m==0 || m==1) v = fmaxf(v, 0.f);
            else if (m==3)    v = 1.f/(1.f+__expf(-v));
            dst[(size_t)row*DD + jh*64 + ci + 16*cc] = v;
        }
    }
}

// ---------------------------------------------------------------------------
// Kernel 2: per (chunk, j-quarter) postprocess. 1024 blocks, 28KB LDS
// -> 4 blocks/CU, 16 waves/CU. cumprod + kb computed per block (full i);
// each block writes its j-quarter of kh, qc, U. jq==0 writes cL, Ksum.
// ---------------------------------------------------------------------------
__global__ __launch_bounds__(256) void k_chunk(float* __restrict__ ws)
{
    __shared__ float ksm[LL][DD];   // relu'd k (full)
    __shared__ float gs [LL][DD];   // gate -> in-place cumprod c (full)
    __shared__ float kbs[LL][DD];   // kb (full)
    __shared__ float qs [LL][32];   // q quarter
    __shared__ float vs [LL][32];   // v quarter

    const int tid = threadIdx.x;
    const int bq_ = blockIdx.x;        // bc*4 + jq
    const int bc  = bq_ >> 2;
    const int jq  = bq_ & 3;
    const int jbase = jq * 32;
    const int b   = bc / CC;
    const int t0  = (bc % CC) * LL;
    const size_t tile = (size_t)(b*TT + t0)*DD;

    // stage k,g full tiles (512 f4 each)
    {
        const float4* kg = (const float4*)(ws + OFF_KH + tile);
        const float4* gg = (const float4*)(ws + OFF_G  + tile);
        #pragma unroll
        for (int r=0;r<2;r++){
            int f = tid + r*256;
            int t = f >> 5, c4 = (f & 31)*4;
            *(float4*)&ksm[t][c4] = kg[f];
            *(float4*)&gs [t][c4] = gg[f];
        }
        // stage q,v quarters (128 f4 each)
        int f  = tid & 127;
        int t  = f >> 3, c = (f & 7)*4;
        const float* src = (tid < 128) ? (ws + OFF_QC) : (ws + OFF_V);
        float4 v4 = *(const float4*)(src + tile + (size_t)t*DD + jbase + c);
        if (tid < 128) *(float4*)&qs[t][c] = v4;
        else           *(float4*)&vs[t][c] = v4;
    }
    __syncthreads();

    // cumprod per column i (full)
    if (tid < DD){
        float c = 1.f;
        #pragma unroll
        for (int t=0;t<LL;t++){ c *= gs[t][tid]; gs[t][tid] = c; }
        if (jq == 0) ws[OFF_CL + (size_t)bc*DD + tid] = c;
    }
    __syncthreads();

    if (tid < DD){                     // kb full; write kh for own quarter
        const int i = tid;
        const float cl = gs[LL-1][i];
        const bool own = (i >= jbase) && (i < jbase+32);
        float ksum = 0.f;
        float* khg = ws + OFF_KH + tile;
        #pragma unroll
        for (int t=0;t<LL;t++){
            float kh = ksm[t][i] / gs[t][i];
            if (own) khg[t*DD + i] = kh;
            float kb = kh * cl;
            kbs[t][i] = kb;
            ksum += kb;
        }
        if (jq == 0) ws[OFF_KS + (size_t)bc*DD + i] = ksum;
    } else {                           // qc for own quarter: 32 j x 4 t-groups
        const int j  = tid & 31;
        const int tg = (tid - 128) >> 5;   // 0..3
        float* qcg = ws + OFF_QC + tile;
        #pragma unroll
        for (int tt=0;tt<4;tt++){
            int t = tg*4 + tt;
            qcg[t*DD + jbase + j] = qs[t][j] * gs[t][jbase + j];
        }
    }
    __syncthreads();

    // U[i][jbase+j] = sum_u kb[u][i]*v[u][j];  thread = (j=tid&31, ih=tid>>5)
    const int j  = tid & 31;
    const int ih = tid >> 5;           // 0..7 -> i range ih*16..+16
    float vr[LL];
    #pragma unroll
    for (int u=0;u<LL;u++) vr[u]=vs[u][j];
    float* Ug = ws + OFF_U + (size_t)bc*DD*DD;
    #pragma unroll
    for (int i4=0;i4<4;i4++){
        int i = ih*16 + i4*4;
        float a0=0.f,a1=0.f,a2=0.f,a3=0.f;
        #pragma unroll
        for (int u=0;u<LL;u++){
            float4 kb4 = *(const float4*)(&kbs[u][i]);
            float vu = vr[u];
            a0 = fmaf(kb4.x,vu,a0); a1 = fmaf(kb4.y,vu,a1);
            a2 = fmaf(kb4.z,vu,a2); a3 = fmaf(kb4.w,vu,a3);
        }
        Ug[(size_t)(i+0)*DD + jbase + j]=a0; Ug[(size_t)(i+1)*DD + jbase + j]=a1;
        Ug[(size_t)(i+2)*DD + jbase + j]=a2; Ug[(size_t)(i+3)*DD + jbase + j]=a3;
    }
}

// ---------------------------------------------------------------------------
// Kernel 3: per-element scan over chunks, 16-deep prefetch ring.
// 512 blocks x 128 threads.
// ---------------------------------------------------------------------------
__global__ __launch_bounds__(128) void k_scan(float* __restrict__ ws)
{
    __shared__ float cls[CC], kss[CC];
    const int bi = blockIdx.x;      // b*DD + i
    const int b  = bi >> 7;
    const int i  = bi & 127;
    const int j  = threadIdx.x;

    if (j < CC) cls[j]      = ws[OFF_CL + (size_t)(b*CC + j)*DD + i];
    else        kss[j - CC] = ws[OFF_KS + (size_t)(b*CC + j - CC)*DD + i];
    __syncthreads();

    const float* U  = ws + OFF_U;
    float*       s0 = ws + OFF_S0;
    float*       z0 = ws + OFF_Z0;
    const size_t base = (size_t)b*CC*DD*DD + (size_t)i*DD + j;

    float up[16];
    #pragma unroll
    for (int p=0;p<16;p++) up[p] = U[base + (size_t)p*DD*DD];

    float s = 0.f, z = 0.f;
    #pragma unroll
    for (int ch=0; ch<CC; ch++){
        s0[base + (size_t)ch*DD*DD] = s;
        if (j==0) z0[(size_t)(b*CC+ch)*DD + i] = z;
        float u  = up[ch & 15];
        if (ch + 16 < CC) up[ch & 15] = U[base + (size_t)(ch+16)*DD*DD];
        float cl = cls[ch];
        s = fmaf(cl, s, u);
        z = fmaf(cl, z, kss[ch]);
    }
}

// ---------------------------------------------------------------------------
// Kernel 4: per (chunk, j-half) output. 512 blocks, ~40KB LDS -> 2/CU.
// scores+den computed per block (full k); y for own 64-col half.
// ---------------------------------------------------------------------------
__global__ __launch_bounds__(256) void k_out(const float* __restrict__ ws, float* __restrict__ y)
{
    __shared__ float qcs[LL][DD+4];
    __shared__ float khs[LL][DD+4];
    __shared__ float vsm[LL][64+4];
    __shared__ float Ss[LL][LL];
    __shared__ float denS[LL];
    __shared__ float z0s[DD];
    __shared__ float s0s[2][32][64+4];

    const int tid = threadIdx.x;
    const int bh  = blockIdx.x;        // bc*2 + jh
    const int bc  = bh >> 1;
    const int jh  = bh & 1;
    const int jbase = jh * 64;
    const int b   = bc / CC;
    const int ch  = bc % CC;
    const int t0  = ch * LL;
    const size_t tile = (size_t)(b*TT + t0)*DD;
    const float* s0g = ws + OFF_S0 + (size_t)bc*DD*DD;

    float4 pre[2];
    {
        const float4* qcg = (const float4*)(ws + OFF_QC + tile);
        const float4* khg = (const float4*)(ws + OFF_KH + tile);
        #pragma unroll
        for (int rep=0; rep<2; rep++){
            int f = tid + rep*256;
            int t = f >> 5, k4 = f & 31;
            *(float4*)&qcs[t][k4*4] = qcg[f];
            *(float4*)&khs[t][k4*4] = khg[f];
        }
        {   // v half: [16][64] = 256 f4
            int t = tid >> 4, c = (tid & 15)*4;
            *(float4*)&vsm[t][c] =
                *(const float4*)(ws + OFF_V + tile + (size_t)t*DD + jbase + c);
        }
        if (tid < DD) z0s[tid] = ws[OFF_Z0 + (size_t)bc*DD + tid];
        // slice 0 of s0 col-half: [32][64] = 512 f4
        #pragma unroll
        for (int r=0;r<2;r++){
            int f = tid + r*256;
            int row = f >> 4, c4 = (f & 15)*4;
            pre[r] = *(const float4*)(s0g + (size_t)row*DD + jbase + c4);
        }
    }
    __syncthreads();

    // scores S[t][u] = qc_t . kh_u (full 128-dot), masked u<=t
    {
        int t = tid >> 4, u = tid & 15;
        float s = 0.f;
        #pragma unroll 8
        for (int k4=0; k4<32; k4++){
            float4 q4 = *(const float4*)&qcs[t][k4*4];
            float4 h4 = *(const float4*)&khs[u][k4*4];
            s = fmaf(q4.x,h4.x, fmaf(q4.y,h4.y, fmaf(q4.z,h4.z, fmaf(q4.w,h4.w, s))));
        }
        Ss[t][u] = (u <= t) ? s : 0.f;
    }
    __syncthreads();

    if (tid < LL){
        int t = tid;
        float d = EPSV;
        for (int u=0; u<=t; u++) d += Ss[t][u];
        #pragma unroll 8
        for (int kk=0; kk<DD; kk++) d += qcs[t][kk]*z0s[kk];
        denS[t] = d;
    }

    const int t  = tid >> 4;
    const int jg = tid & 15;
    const int j0 = jg * 4;             // within the 64-col half
    float y4[4] = {0.f,0.f,0.f,0.f};

    __syncthreads();
    // intra-chunk: S @ V (half)
    #pragma unroll
    for (int u=0; u<LL; u++){
        float sv = Ss[t][u];
        float4 v4 = *(const float4*)&vsm[u][j0];
        y4[0]=fmaf(sv,v4.x,y4[0]); y4[1]=fmaf(sv,v4.y,y4[1]);
        y4[2]=fmaf(sv,v4.z,y4[2]); y4[3]=fmaf(sv,v4.w,y4[3]);
    }

    // inter-chunk: qc @ s0 (col-half), 4 slices of 32 rows, double-buffered
    #pragma unroll
    for (int sl=0; sl<4; sl++){
        __syncthreads();
        #pragma unroll
        for (int r=0;r<2;r++){
            int f = tid + r*256;
            *(float4*)&s0s[sl&1][f>>4][(f&15)*4] = pre[r];
        }
        if (sl < 3){
            #pragma unroll
            for (int r=0;r<2;r++){
                int f = tid + r*256;
                int row = f >> 4, c4 = (f & 15)*4;
                pre[r] = *(const float4*)(s0g + (size_t)((sl+1)*32 + row)*DD + jbase + c4);
            }
        }
        __syncthreads();
        #pragma unroll 8
        for (int ii=0; ii<32; ii++){
            float qv = qcs[t][sl*32+ii];
            float4 s4 = *(const float4*)&s0s[sl&1][ii][j0];
            y4[0]=fmaf(qv,s4.x,y4[0]); y4[1]=fmaf(qv,s4.y,y4[1]);
            y4[2]=fmaf(qv,s4.z,y4[2]); y4[3]=fmaf(qv,s4.w,y4[3]);
        }
    }

    const float rd = 1.f/denS[t];
    float* yg = y + tile + (size_t)t*DD + jbase + j0;
    *(float4*)yg = make_float4(y4[0]*rd, y4[1]*rd, y4[2]*rd, y4[3]*rd);
}

extern "C" void kernel_launch(void* const* d_in, const int* in_sizes, int n_in,
                              void* d_out, int out_size, void* d_ws, size_t ws_size,
                              hipStream_t stream)
{
    const float* x  = (const float*)d_in[0];
    const float* Wq = (const float*)d_in[1]; const float* bq = (const float*)d_in[2];
    const float* Wk = (const float*)d_in[3]; const float* bk = (const float*)d_in[4];
    const float* Wv = (const float*)d_in[5]; const float* bv = (const float*)d_in[6];
    const float* Wa = (const float*)d_in[7]; const float* ba = (const float*)d_in[8];
    float* ws = (float*)d_ws;
    float* yo = (float*)d_out;

    hipLaunchKernelGGL(k_gemm,  dim3(1024),    dim3(256), 0, stream,
                       x, Wq,bq, Wk,bk, Wv,bv, Wa,ba, ws);
    hipLaunchKernelGGL(k_chunk, dim3(BB*CC*4), dim3(256), 0, stream, ws);
    hipLaunchKernelGGL(k_scan,  dim3(BB*DD),   dim3(128), 0, stream, ws);
    hipLaunchKernelGGL(k_out,   dim3(BB*CC*2), dim3(256), 0, stream, ws, yo);
}